// Round 6
// baseline (1503.978 us; speedup 1.0000x reference)
//
#include <hip/hip_runtime.h>
#include <cstdint>
#include <cstddef>

typedef __bf16 bf16;
typedef __bf16 bf16x8 __attribute__((ext_vector_type(8)));
typedef float  f32x4  __attribute__((ext_vector_type(4)));

#define MFMA(A, B, C) __builtin_amdgcn_mfma_f32_16x16x32_bf16(A, B, C, 0, 0, 0)

__device__ __forceinline__ void gload_lds16(const void* g, void* l) {
  __builtin_amdgcn_global_load_lds((const __attribute__((address_space(1))) void*)g,
                                   (__attribute__((address_space(3))) void*)l, 16, 0, 0);
}

// ---------------- convert x (fp32 -> bf16), 8 elems/thread ----------------
__global__ __launch_bounds__(256) void k_cvt_x(const float* __restrict__ x,
                                               bf16* __restrict__ xb) {
  int i = blockIdx.x * 256 + threadIdx.x;  // 2,097,152 threads exactly
  const float4* p = (const float4*)x;
  float4 a = p[i * 2 + 0], b = p[i * 2 + 1];
  bf16x8 o;
  o[0] = (bf16)a.x; o[1] = (bf16)a.y; o[2] = (bf16)a.z; o[3] = (bf16)a.w;
  o[4] = (bf16)b.x; o[5] = (bf16)b.y; o[6] = (bf16)b.z; o[7] = (bf16)b.w;
  ((bf16x8*)xb)[i] = o;
}

// ------- convert + transpose W: wt[j][k] = W_sel[k][j&1023], j in [0,3072) -------
__global__ __launch_bounds__(256) void k_cvt_w(const float* __restrict__ Wq,
                                               const float* __restrict__ Wk,
                                               const float* __restrict__ Wv,
                                               bf16* __restrict__ wt) {
  int t = blockIdx.x * 256 + threadIdx.x;  // 393,216 exactly
  int j = t >> 7;
  int ko = (t & 127) << 3;
  const float* W = (j < 1024) ? Wq : (j < 2048) ? Wk : Wv;
  int jl = j & 1023;
  bf16x8 o;
#pragma unroll
  for (int e = 0; e < 8; ++e) o[e] = (bf16)W[(size_t)(ko + e) * 1024 + jl];
  *(bf16x8*)(wt + (size_t)j * 1024 + ko) = o;
}

// ---------------- fused QKV GEMM: C[16384][3072] = xb @ wt^T ----------------
__global__ __launch_bounds__(256, 2)
void k_qkv(const bf16* __restrict__ xb, const bf16* __restrict__ wt,
           const float* __restrict__ bq, const float* __restrict__ bk,
           const float* __restrict__ bv,
           bf16* __restrict__ q, bf16* __restrict__ k, bf16* __restrict__ v) {
  __shared__ bf16 As[128 * 64];
  __shared__ bf16 Bs[128 * 64];
  const int tid = threadIdx.x, lane = tid & 63, w = tid >> 6;
  const int wm = w >> 1, wn = w & 1;
  const int bm = blockIdx.x, bn = blockIdx.y;

  f32x4 acc[16];
#pragma unroll
  for (int i = 0; i < 16; ++i) acc[i] = f32x4{0.f, 0.f, 0.f, 0.f};

  for (int kt = 0; kt < 16; ++kt) {
    __syncthreads();
#pragma unroll
    for (int i = 0; i < 4; ++i) {
      int chunk = (w * 4 + i) * 64 + lane;
      int row = chunk >> 3, ch = chunk & 7;
      size_t gofs = ((size_t)row * 1024 + (size_t)kt * 64) * 2 + (size_t)((ch ^ (row & 7)) << 4);
      gload_lds16((const char*)(xb + (size_t)bm * 128 * 1024) + gofs,
                  (char*)As + (w * 4 + i) * 1024);
      gload_lds16((const char*)(wt + (size_t)bn * 128 * 1024) + gofs,
                  (char*)Bs + (w * 4 + i) * 1024);
    }
    __syncthreads();
#pragma unroll
    for (int s = 0; s < 2; ++s) {
      bf16x8 af[4], bf_[4];
#pragma unroll
      for (int mi = 0; mi < 4; ++mi) {
        int row = wm * 64 + mi * 16 + (lane & 15);
        af[mi] = *(const bf16x8*)((const char*)As +
                  ((row * 128 + s * 64 + (lane >> 4) * 16) ^ ((row & 7) << 4)));
      }
#pragma unroll
      for (int ni = 0; ni < 4; ++ni) {
        int row = wn * 64 + ni * 16 + (lane & 15);
        bf_[ni] = *(const bf16x8*)((const char*)Bs +
                  ((row * 128 + s * 64 + (lane >> 4) * 16) ^ ((row & 7) << 4)));
      }
#pragma unroll
      for (int mi = 0; mi < 4; ++mi)
#pragma unroll
        for (int ni = 0; ni < 4; ++ni)
          acc[mi * 4 + ni] = MFMA(af[mi], bf_[ni], acc[mi * 4 + ni]);
    }
  }
  const int jsel = bn >> 3;  // 0:Q 1:K 2:V
  const float* bias = jsel == 0 ? bq : jsel == 1 ? bk : bv;
  bf16* outp = jsel == 0 ? q : jsel == 1 ? k : v;
  const float scale = jsel == 0 ? 0.03125f : 1.0f;
#pragma unroll
  for (int ni = 0; ni < 4; ++ni) {
    int col = bn * 128 + wn * 64 + ni * 16 + (lane & 15);
    int jl = col & 1023;
    float bsv = bias[jl];
#pragma unroll
    for (int mi = 0; mi < 4; ++mi) {
#pragma unroll
      for (int e = 0; e < 4; ++e) {
        int tok = bm * 128 + wm * 64 + mi * 16 + (lane >> 4) * 4 + e;
        outp[(size_t)tok * 1024 + jl] = (bf16)((acc[mi * 4 + ni][e] + bsv) * scale);
      }
    }
  }
}

// ---------------- V transpose: vt[b][d][n] = v[b][n][d] ----------------
__global__ __launch_bounds__(256)
void k_trv(const bf16* __restrict__ v, bf16* __restrict__ vt) {
  __shared__ bf16 tl[64][80];
  const int n0 = blockIdx.x * 64, d0 = blockIdx.y * 64, b = blockIdx.z;
  const int tid = threadIdx.x;
#pragma unroll
  for (int it = 0; it < 2; ++it) {
    int task = tid + it * 256;
    int row = task >> 3, oct = task & 7;
    *(bf16x8*)&tl[row][oct * 8] =
        *(const bf16x8*)(v + ((size_t)(b * 2048 + n0 + row) * 1024 + d0 + oct * 8));
  }
  __syncthreads();
#pragma unroll
  for (int it = 0; it < 2; ++it) {
    int task = tid + it * 256;
    int dr = task >> 3, noct = task & 7;
    bf16x8 o;
#pragma unroll
    for (int e = 0; e < 8; ++e) o[e] = tl[noct * 8 + e][dr];
    *(bf16x8*)(vt + ((size_t)(b * 1024 + d0 + dr) * 2048 + n0 + noct * 8)) = o;
  }
}

// ---------------- flash attention, counted-vmcnt pipeline (T3+T4) ----------------
// 1-D grid 256; b = blockIdx.x & 7 pins each batch to one XCD (T1).
// Q d<512 in 64 VGPRs, d>=512 in 64KB swizzled LDS (loaded ONCE).
// 16 chunk-phases/kt, 3 LDS buffers, depth-2 prefetch, raw s_barrier +
// manual vmcnt(2) — loads stay in flight across barriers (never drain
// to 0 in the main loop; only kt==31 drains).
__global__ __launch_bounds__(512, 1)
void k_attn(const bf16* __restrict__ Q, const bf16* __restrict__ K,
            const bf16* __restrict__ Vt, const int* __restrict__ mask,
            float* __restrict__ O) {
  __shared__ bf16  KV[3][64 * 128];   // 48KB: chunk ring buffers
  __shared__ float Sl[64 * 64];       // 16KB
  __shared__ bf16  Pl[64 * 64];       // 8KB
  __shared__ bf16  Qs[64 * 512];      // 64KB: Q d in [512,1024), swizzled
  __shared__ int   Ml[2048];          // 8KB: mask row
  __shared__ float ml[64], ll[64], al[64];

  const int b = blockIdx.x & 7;             // XCD pin: linear id % 8 = XCD
  const int q0 = (blockIdx.x >> 3) * 64;
  const int tid = threadIdx.x, lane = tid & 63, w = tid >> 6;
  const int l15 = lane & 15, l4 = lane >> 4;
  const int wq = w >> 1, wk = w & 1;

  const bf16* Qb = Q + (size_t)(b * 2048 + q0 + wq * 16 + l15) * 1024 + l4 * 8;
  const bf16* Kb = K + (size_t)(b * 2048) * 1024;
  const bf16* Vb = Vt + (size_t)(b * 1024) * 2048;

  f32x4 oacc[32];  // [dc 0..7][i 0..3]: d = dc*128 + wk*64 + i*16 + l15
#pragma unroll
  for (int i = 0; i < 32; ++i) oacc[i] = f32x4{0.f, 0.f, 0.f, 0.f};

  // stage chunk gc (0..511): kt=gc>>4, c=gc&15; c<8: K d-chunk c, else V d-chunk c-8.
  // 2 gload_lds per wave; LDS dest wave-uniform (HW adds lane*16).
  auto stage = [&](int gc) {
    int skt = gc >> 4, c = gc & 15;
    char* dst = (char*)KV[gc % 3];
    if (c < 8) {
#pragma unroll
      for (int j = 0; j < 2; ++j) {
        int ubase = j * 512 + w * 64;
        int unit = ubase + lane;
        int key = unit >> 4, u = unit & 15;
        gload_lds16(Kb + (size_t)(skt * 64 + key) * 1024 + c * 128 + ((u ^ (key & 7)) << 3),
                    dst + ubase * 16);
      }
    } else {
#pragma unroll
      for (int j = 0; j < 2; ++j) {
        int ubase = j * 512 + w * 64;
        int unit = ubase + lane;
        int d = unit >> 3, u = unit & 7;
        gload_lds16(Vb + (size_t)((c - 8) * 128 + d) * 2048 + skt * 64 + ((u ^ (d & 7)) << 3),
                    dst + ubase * 16);
      }
    }
  };

  // ---- prologue: stats init, mask->LDS, Q(d>=512)->LDS, Q(d<512)->regs, 2 chunks ----
  if (tid < 64) { ml[tid] = -1e30f; ll[tid] = 0.f; al[tid] = 1.f; }
  {
    int4 m4 = *(const int4*)(mask + b * 2048 + tid * 4);
    *(int4*)&Ml[tid * 4] = m4;
  }
#pragma unroll
  for (int j = 0; j < 8; ++j) {             // Qs: 4096 units of 16B, 8/wave-iter
    int ubase = w * 512 + j * 64;
    int unit = ubase + lane;
    int qrow = unit >> 6, slot = unit & 63; // 64 units per 1KB row
    gload_lds16(Q + (size_t)(b * 2048 + q0 + qrow) * 1024 + 512 + ((slot ^ (qrow & 7)) << 3),
                (char*)Qs + ubase * 16);
  }
  bf16x8 aqr[16];                           // Q d<512: [dc 0..3][ks 0..3]
#pragma unroll
  for (int dc = 0; dc < 4; ++dc)
#pragma unroll
    for (int ks = 0; ks < 4; ++ks)
      aqr[dc * 4 + ks] = *(const bf16x8*)(Qb + dc * 128 + ks * 32);
  stage(0);
  stage(1);
  asm volatile("s_waitcnt vmcnt(2) lgkmcnt(0)" ::: "memory");
  __builtin_amdgcn_s_barrier();

  for (int kt = 0; kt < 32; ++kt) {
    const int base = kt * 16;
    // ---- phase 1: S = Q @ K^T, 8 K-chunk phases ----
    f32x4 s0a{0,0,0,0}, s0b{0,0,0,0}, s1a{0,0,0,0}, s1b{0,0,0,0};
#pragma unroll
    for (int dc = 0; dc < 8; ++dc) {
      const int gc = base + dc;
      if (gc + 2 < 512) stage(gc + 2);
      bf16x8 aq[4];
      if (dc < 4) {
#pragma unroll
        for (int ks = 0; ks < 4; ++ks) aq[ks] = aqr[dc * 4 + ks];
      } else {
        int qrow = wq * 16 + l15;
#pragma unroll
        for (int ks = 0; ks < 4; ++ks) {
          int slot = (dc - 4) * 16 + ks * 4 + l4;
          aq[ks] = *(const bf16x8*)((const char*)Qs +
                    (qrow * 1024 + ((slot ^ (qrow & 7)) << 4)));
        }
      }
      const char* kb = (const char*)KV[gc % 3];
      const int k0 = wk * 32 + l15, k1 = k0 + 16;
      __builtin_amdgcn_s_setprio(1);
#pragma unroll
      for (int ks = 0; ks < 4; ++ks) {
        bf16x8 b0 = *(const bf16x8*)(kb + (k0 * 256 + (((ks * 4 + l4) ^ (k0 & 7)) << 4)));
        bf16x8 b1 = *(const bf16x8*)(kb + (k1 * 256 + (((ks * 4 + l4) ^ (k1 & 7)) << 4)));
        if (ks & 1) { s0b = MFMA(aq[ks], b0, s0b); s1b = MFMA(aq[ks], b1, s1b); }
        else        { s0a = MFMA(aq[ks], b0, s0a); s1a = MFMA(aq[ks], b1, s1a); }
      }
      __builtin_amdgcn_s_setprio(0);
      if (dc == 7) {  // write S tile before this phase's barrier
        f32x4 sf0, sf1;
#pragma unroll
        for (int e = 0; e < 4; ++e) { sf0[e] = s0a[e] + s0b[e]; sf1[e] = s1a[e] + s1b[e]; }
#pragma unroll
        for (int e = 0; e < 4; ++e) {
          int qr = wq * 16 + l4 * 4 + e;
          *(float*)((char*)Sl + ((qr * 256 + k0 * 4) ^ ((qr & 7) << 4))) = sf0[e];
          *(float*)((char*)Sl + ((qr * 256 + k1 * 4) ^ ((qr & 7) << 4))) = sf1[e];
        }
      }
      if (kt < 31) asm volatile("s_waitcnt vmcnt(2)" ::: "memory");
      else         asm volatile("s_waitcnt vmcnt(0)" ::: "memory");
      if (dc == 7) asm volatile("s_waitcnt lgkmcnt(0)" ::: "memory");
      __builtin_amdgcn_s_barrier();
    }
    // ---- phase 2: online softmax with defer-max (8 threads/row), mask from LDS ----
    {
      int r = tid >> 3, g = tid & 7;
      f32x4 sa = *(const f32x4*)((const char*)Sl + ((r * 256 + g * 32) ^ ((r & 7) << 4)));
      f32x4 sb = *(const f32x4*)((const char*)Sl + ((r * 256 + g * 32 + 16) ^ ((r & 7) << 4)));
      float s[8];
#pragma unroll
      for (int j = 0; j < 4; ++j) { s[j] = sa[j]; s[j + 4] = sb[j]; }
      const int* mrow = Ml + kt * 64 + g * 8;
      float mx = -1e30f;
      int mk[8];
#pragma unroll
      for (int j = 0; j < 8; ++j) {
        mk[j] = mrow[j];
        s[j] = mk[j] ? s[j] : -1e30f;
        mx = fmaxf(mx, s[j]);
      }
      mx = fmaxf(mx, __shfl_xor(mx, 1, 8));
      mx = fmaxf(mx, __shfl_xor(mx, 2, 8));
      mx = fmaxf(mx, __shfl_xor(mx, 4, 8));
      float mo = ml[r];
      float mn = mo, alpha = 1.f;
      if (mx > mo + 8.f) { mn = mx; alpha = __expf(mo - mn); }  // defer-max (T13)
      float sum = 0.f;
      bf16x8 pb;
#pragma unroll
      for (int j = 0; j < 8; ++j) {
        float p = mk[j] ? __expf(s[j] - mn) : 0.f;
        sum += p;
        pb[j] = (bf16)p;
      }
      sum += __shfl_xor(sum, 1, 8);
      sum += __shfl_xor(sum, 2, 8);
      sum += __shfl_xor(sum, 4, 8);
      if (g == 0) { ml[r] = mn; ll[r] = ll[r] * alpha + sum; al[r] = alpha; }
      *(bf16x8*)((char*)Pl + ((r * 128 + g * 16) ^ ((r & 7) << 4))) = pb;
    }
    asm volatile("s_waitcnt lgkmcnt(0)" ::: "memory");
    __builtin_amdgcn_s_barrier();
    __builtin_amdgcn_sched_barrier(0);
    // ---- rescale O (skipped when alpha==1 for all 4 owned rows) ----
    {
      float av[4];
#pragma unroll
      for (int e = 0; e < 4; ++e) av[e] = al[wq * 16 + l4 * 4 + e];
      if (av[0] != 1.f || av[1] != 1.f || av[2] != 1.f || av[3] != 1.f) {
#pragma unroll
        for (int i = 0; i < 32; ++i)
#pragma unroll
          for (int e = 0; e < 4; ++e) oacc[i][e] *= av[e];
      }
    }
    // P A-frags (reused across all 8 V-chunk phases)
    bf16x8 pa0, pa1;
    {
      int prow = wq * 16 + l15;
      pa0 = *(const bf16x8*)((const char*)Pl + ((prow * 128 + l4 * 16) ^ ((prow & 7) << 4)));
      pa1 = *(const bf16x8*)((const char*)Pl + ((prow * 128 + 64 + l4 * 16) ^ ((prow & 7) << 4)));
    }
    // ---- phase 3: O += P @ V, 8 V-chunk phases ----
#pragma unroll
    for (int dc = 0; dc < 8; ++dc) {
      const int gc = base + 8 + dc;
      if (gc + 2 < 512) stage(gc + 2);
      const char* vb = (const char*)KV[gc % 3];
      __builtin_amdgcn_s_setprio(1);
#pragma unroll
      for (int i = 0; i < 4; ++i) {
        int d = wk * 64 + i * 16 + l15;
        bf16x8 v0 = *(const bf16x8*)(vb + (d * 128 + ((l4 ^ (d & 7)) << 4)));
        bf16x8 v1 = *(const bf16x8*)(vb + (d * 128 + (((4 + l4) ^ (d & 7)) << 4)));
        oacc[dc * 4 + i] = MFMA(pa0, v0, oacc[dc * 4 + i]);
        oacc[dc * 4 + i] = MFMA(pa1, v1, oacc[dc * 4 + i]);
      }
      __builtin_amdgcn_s_setprio(0);
      if (kt < 31) asm volatile("s_waitcnt vmcnt(2)" ::: "memory");
      else         asm volatile("s_waitcnt vmcnt(0)" ::: "memory");
      __builtin_amdgcn_s_barrier();
    }
  }
  // ---- epilogue: O / l -> fp32 out ----
  float li[4];
#pragma unroll
  for (int e = 0; e < 4; ++e) li[e] = 1.0f / ll[wq * 16 + l4 * 4 + e];
#pragma unroll
  for (int dc = 0; dc < 8; ++dc) {
#pragma unroll
    for (int i = 0; i < 4; ++i) {
      int d = dc * 128 + wk * 64 + i * 16 + l15;
#pragma unroll
      for (int e = 0; e < 4; ++e) {
        int qr = q0 + wq * 16 + l4 * 4 + e;
        O[(size_t)(b * 2048 + qr) * 1024 + d] = oacc[dc * 4 + i][e] * li[e];
      }
    }
  }
}

extern "C" void kernel_launch(void* const* d_in, const int* in_sizes, int n_in,
                              void* d_out, int out_size, void* d_ws, size_t ws_size,
                              hipStream_t stream) {
  const float* x  = (const float*)d_in[0];
  const int* mask = (const int*)d_in[1];
  const float* Wq = (const float*)d_in[2];
  const float* bq = (const float*)d_in[3];
  const float* Wk = (const float*)d_in[4];
  const float* bk = (const float*)d_in[5];
  const float* Wv = (const float*)d_in[6];
  const float* bv = (const float*)d_in[7];
  float* out = (float*)d_out;

  char* ws = (char*)d_ws;
  bf16* xb = (bf16*)(ws);
  bf16* wt = (bf16*)(ws + 33554432);
  bf16* q  = (bf16*)(ws + 33554432 + 6291456);
  bf16* k  = (bf16*)(ws + 73400320);
  bf16* v  = (bf16*)(ws + 106954752);
  bf16* vt = xb;  // xb dead after k_qkv

  k_cvt_x<<<8192, 256, 0, stream>>>(x, xb);
  k_cvt_w<<<1536, 256, 0, stream>>>(Wq, Wk, Wv, wt);
  k_qkv<<<dim3(128, 24), 256, 0, stream>>>(xb, wt, bq, bk, bv, q, k, v);
  k_trv<<<dim3(32, 16, 8), 256, 0, stream>>>(v, vt);
  k_attn<<<256, 512, 0, stream>>>(q, k, vt, mask, out);
}

// Round 7
// 443.644 us; speedup vs baseline: 3.3901x; 3.3901x over previous
//
#include <hip/hip_runtime.h>
#include <cstdint>
#include <cstddef>

typedef __bf16 bf16;
typedef __bf16 bf16x8 __attribute__((ext_vector_type(8)));
typedef float  f32x4  __attribute__((ext_vector_type(4)));

#define MFMA(A, B, C) __builtin_amdgcn_mfma_f32_16x16x32_bf16(A, B, C, 0, 0, 0)

__device__ __forceinline__ void gload_lds16(const void* g, void* l) {
  __builtin_amdgcn_global_load_lds((const __attribute__((address_space(1))) void*)g,
                                   (__attribute__((address_space(3))) void*)l, 16, 0, 0);
}

// ---------------- convert x (fp32 -> bf16), 8 elems/thread ----------------
__global__ __launch_bounds__(256) void k_cvt_x(const float* __restrict__ x,
                                               bf16* __restrict__ xb) {
  int i = blockIdx.x * 256 + threadIdx.x;  // 2,097,152 threads exactly
  const float4* p = (const float4*)x;
  float4 a = p[i * 2 + 0], b = p[i * 2 + 1];
  bf16x8 o;
  o[0] = (bf16)a.x; o[1] = (bf16)a.y; o[2] = (bf16)a.z; o[3] = (bf16)a.w;
  o[4] = (bf16)b.x; o[5] = (bf16)b.y; o[6] = (bf16)b.z; o[7] = (bf16)b.w;
  ((bf16x8*)xb)[i] = o;
}

// ------- convert + transpose W: wt[j][k] = W_sel[k][j&1023], j in [0,3072) -------
__global__ __launch_bounds__(256) void k_cvt_w(const float* __restrict__ Wq,
                                               const float* __restrict__ Wk,
                                               const float* __restrict__ Wv,
                                               bf16* __restrict__ wt) {
  int t = blockIdx.x * 256 + threadIdx.x;  // 393,216 exactly
  int j = t >> 7;
  int ko = (t & 127) << 3;
  const float* W = (j < 1024) ? Wq : (j < 2048) ? Wk : Wv;
  int jl = j & 1023;
  bf16x8 o;
#pragma unroll
  for (int e = 0; e < 8; ++e) o[e] = (bf16)W[(size_t)(ko + e) * 1024 + jl];
  *(bf16x8*)(wt + (size_t)j * 1024 + ko) = o;
}

// ---------------- fused QKV GEMM: C[16384][3072] = xb @ wt^T ----------------
__global__ __launch_bounds__(256, 2)
void k_qkv(const bf16* __restrict__ xb, const bf16* __restrict__ wt,
           const float* __restrict__ bq, const float* __restrict__ bk,
           const float* __restrict__ bv,
           bf16* __restrict__ q, bf16* __restrict__ k, bf16* __restrict__ v) {
  __shared__ bf16 As[128 * 64];
  __shared__ bf16 Bs[128 * 64];
  const int tid = threadIdx.x, lane = tid & 63, w = tid >> 6;
  const int wm = w >> 1, wn = w & 1;
  const int bm = blockIdx.x, bn = blockIdx.y;

  f32x4 acc[16];
#pragma unroll
  for (int i = 0; i < 16; ++i) acc[i] = f32x4{0.f, 0.f, 0.f, 0.f};

  for (int kt = 0; kt < 16; ++kt) {
    __syncthreads();
#pragma unroll
    for (int i = 0; i < 4; ++i) {
      int chunk = (w * 4 + i) * 64 + lane;
      int row = chunk >> 3, ch = chunk & 7;
      size_t gofs = ((size_t)row * 1024 + (size_t)kt * 64) * 2 + (size_t)((ch ^ (row & 7)) << 4);
      gload_lds16((const char*)(xb + (size_t)bm * 128 * 1024) + gofs,
                  (char*)As + (w * 4 + i) * 1024);
      gload_lds16((const char*)(wt + (size_t)bn * 128 * 1024) + gofs,
                  (char*)Bs + (w * 4 + i) * 1024);
    }
    __syncthreads();
#pragma unroll
    for (int s = 0; s < 2; ++s) {
      bf16x8 af[4], bf_[4];
#pragma unroll
      for (int mi = 0; mi < 4; ++mi) {
        int row = wm * 64 + mi * 16 + (lane & 15);
        af[mi] = *(const bf16x8*)((const char*)As +
                  ((row * 128 + s * 64 + (lane >> 4) * 16) ^ ((row & 7) << 4)));
      }
#pragma unroll
      for (int ni = 0; ni < 4; ++ni) {
        int row = wn * 64 + ni * 16 + (lane & 15);
        bf_[ni] = *(const bf16x8*)((const char*)Bs +
                  ((row * 128 + s * 64 + (lane >> 4) * 16) ^ ((row & 7) << 4)));
      }
#pragma unroll
      for (int mi = 0; mi < 4; ++mi)
#pragma unroll
        for (int ni = 0; ni < 4; ++ni)
          acc[mi * 4 + ni] = MFMA(af[mi], bf_[ni], acc[mi * 4 + ni]);
    }
  }
  const int jsel = bn >> 3;  // 0:Q 1:K 2:V
  const float* bias = jsel == 0 ? bq : jsel == 1 ? bk : bv;
  bf16* outp = jsel == 0 ? q : jsel == 1 ? k : v;
  const float scale = jsel == 0 ? 0.03125f : 1.0f;
#pragma unroll
  for (int ni = 0; ni < 4; ++ni) {
    int col = bn * 128 + wn * 64 + ni * 16 + (lane & 15);
    int jl = col & 1023;
    float bsv = bias[jl];
#pragma unroll
    for (int mi = 0; mi < 4; ++mi) {
#pragma unroll
      for (int e = 0; e < 4; ++e) {
        int tok = bm * 128 + wm * 64 + mi * 16 + (lane >> 4) * 4 + e;
        outp[(size_t)tok * 1024 + jl] = (bf16)((acc[mi * 4 + ni][e] + bsv) * scale);
      }
    }
  }
}

// ---------------- V transpose: vt[b][d][n] = v[b][n][d] ----------------
__global__ __launch_bounds__(256)
void k_trv(const bf16* __restrict__ v, bf16* __restrict__ vt) {
  __shared__ bf16 tl[64][80];
  const int n0 = blockIdx.x * 64, d0 = blockIdx.y * 64, b = blockIdx.z;
  const int tid = threadIdx.x;
#pragma unroll
  for (int it = 0; it < 2; ++it) {
    int task = tid + it * 256;
    int row = task >> 3, oct = task & 7;
    *(bf16x8*)&tl[row][oct * 8] =
        *(const bf16x8*)(v + ((size_t)(b * 2048 + n0 + row) * 1024 + d0 + oct * 8));
  }
  __syncthreads();
#pragma unroll
  for (int it = 0; it < 2; ++it) {
    int task = tid + it * 256;
    int dr = task >> 3, noct = task & 7;
    bf16x8 o;
#pragma unroll
    for (int e = 0; e < 8; ++e) o[e] = tl[noct * 8 + e][dr];
    *(bf16x8*)(vt + ((size_t)(b * 1024 + d0 + dr) * 2048 + n0 + noct * 8)) = o;
  }
}

// ---------------- S = Q @ K^T (per batch), bf16 out to d_out ----------------
// Same proven 128x128/BK=64 template as k_qkv. A row-stride 1024, B row-stride 1024.
__global__ __launch_bounds__(256, 2)
void k_qk(const bf16* __restrict__ q, const bf16* __restrict__ k,
          bf16* __restrict__ S) {
  __shared__ bf16 As[128 * 64];
  __shared__ bf16 Bs[128 * 64];
  const int tid = threadIdx.x, lane = tid & 63, w = tid >> 6;
  const int wm = w >> 1, wn = w & 1;
  const int bm = blockIdx.x, bn = blockIdx.y, b = blockIdx.z;
  const bf16* Ab = q + (size_t)(b * 2048 + bm * 128) * 1024;
  const bf16* Bb = k + (size_t)(b * 2048 + bn * 128) * 1024;

  f32x4 acc[16];
#pragma unroll
  for (int i = 0; i < 16; ++i) acc[i] = f32x4{0.f, 0.f, 0.f, 0.f};

  for (int kt = 0; kt < 16; ++kt) {
    __syncthreads();
#pragma unroll
    for (int i = 0; i < 4; ++i) {
      int chunk = (w * 4 + i) * 64 + lane;
      int row = chunk >> 3, ch = chunk & 7;
      size_t gofs = ((size_t)row * 1024 + (size_t)kt * 64) * 2 + (size_t)((ch ^ (row & 7)) << 4);
      gload_lds16((const char*)Ab + gofs, (char*)As + (w * 4 + i) * 1024);
      gload_lds16((const char*)Bb + gofs, (char*)Bs + (w * 4 + i) * 1024);
    }
    __syncthreads();
#pragma unroll
    for (int s = 0; s < 2; ++s) {
      bf16x8 af[4], bf_[4];
#pragma unroll
      for (int mi = 0; mi < 4; ++mi) {
        int row = wm * 64 + mi * 16 + (lane & 15);
        af[mi] = *(const bf16x8*)((const char*)As +
                  ((row * 128 + s * 64 + (lane >> 4) * 16) ^ ((row & 7) << 4)));
      }
#pragma unroll
      for (int ni = 0; ni < 4; ++ni) {
        int row = wn * 64 + ni * 16 + (lane & 15);
        bf_[ni] = *(const bf16x8*)((const char*)Bs +
                  ((row * 128 + s * 64 + (lane >> 4) * 16) ^ ((row & 7) << 4)));
      }
#pragma unroll
      for (int mi = 0; mi < 4; ++mi)
#pragma unroll
        for (int ni = 0; ni < 4; ++ni)
          acc[mi * 4 + ni] = MFMA(af[mi], bf_[ni], acc[mi * 4 + ni]);
    }
  }
#pragma unroll
  for (int ni = 0; ni < 4; ++ni) {
    int col = bn * 128 + wn * 64 + ni * 16 + (lane & 15);
#pragma unroll
    for (int mi = 0; mi < 4; ++mi) {
#pragma unroll
      for (int e = 0; e < 4; ++e) {
        int qr = bm * 128 + wm * 64 + mi * 16 + (lane >> 4) * 4 + e;
        S[(size_t)(b * 2048 + qr) * 2048 + col] = (bf16)acc[mi * 4 + ni][e];
      }
    }
  }
}

// ---------------- row softmax: P[row] = softmax(mask(S[row])) ----------------
// One 256-thread block per row (16384 rows); 8 elems/thread.
__global__ __launch_bounds__(256)
void k_sm(const bf16* __restrict__ S, const int* __restrict__ mask,
          bf16* __restrict__ P) {
  __shared__ float redm[4], reds[4];
  const int row = blockIdx.x;
  const int b = row >> 11;
  const int t = threadIdx.x;
  bf16x8 sv = ((const bf16x8*)(S + (size_t)row * 2048))[t];
  int4 m0 = *(const int4*)(mask + b * 2048 + t * 8);
  int4 m1 = *(const int4*)(mask + b * 2048 + t * 8 + 4);
  int mk[8] = {m0.x, m0.y, m0.z, m0.w, m1.x, m1.y, m1.z, m1.w};
  float s[8];
  float mx = -1e30f;
#pragma unroll
  for (int j = 0; j < 8; ++j) {
    s[j] = mk[j] ? (float)sv[j] : -1e30f;
    mx = fmaxf(mx, s[j]);
  }
#pragma unroll
  for (int off = 1; off < 64; off <<= 1) mx = fmaxf(mx, __shfl_xor(mx, off));
  if ((t & 63) == 0) redm[t >> 6] = mx;
  __syncthreads();
  mx = fmaxf(fmaxf(redm[0], redm[1]), fmaxf(redm[2], redm[3]));
  float p[8], sum = 0.f;
#pragma unroll
  for (int j = 0; j < 8; ++j) {
    p[j] = mk[j] ? __expf(s[j] - mx) : 0.f;
    sum += p[j];
  }
#pragma unroll
  for (int off = 1; off < 64; off <<= 1) sum += __shfl_xor(sum, off);
  if ((t & 63) == 0) reds[t >> 6] = sum;
  __syncthreads();
  sum = reds[0] + reds[1] + reds[2] + reds[3];
  float inv = sum > 0.f ? 1.f / sum : 0.f;
  bf16x8 pv;
#pragma unroll
  for (int j = 0; j < 8; ++j) pv[j] = (bf16)(p[j] * inv);
  ((bf16x8*)(P + (size_t)row * 2048))[t] = pv;
}

// ---------------- O = P @ V (per batch), fp32 out ----------------
// A row-stride 2048 (P), B row-stride 2048 (vt), K-dim = 2048 keys.
__global__ __launch_bounds__(256, 2)
void k_pv(const bf16* __restrict__ P, const bf16* __restrict__ vt,
          float* __restrict__ O) {
  __shared__ bf16 As[128 * 64];
  __shared__ bf16 Bs[128 * 64];
  const int tid = threadIdx.x, lane = tid & 63, w = tid >> 6;
  const int wm = w >> 1, wn = w & 1;
  const int bm = blockIdx.x, bn = blockIdx.y, b = blockIdx.z;
  const bf16* Ab = P + (size_t)(b * 2048 + bm * 128) * 2048;
  const bf16* Bb = vt + (size_t)(b * 1024 + bn * 128) * 2048;

  f32x4 acc[16];
#pragma unroll
  for (int i = 0; i < 16; ++i) acc[i] = f32x4{0.f, 0.f, 0.f, 0.f};

  for (int kt = 0; kt < 32; ++kt) {
    __syncthreads();
#pragma unroll
    for (int i = 0; i < 4; ++i) {
      int chunk = (w * 4 + i) * 64 + lane;
      int row = chunk >> 3, ch = chunk & 7;
      size_t gofs = ((size_t)row * 2048 + (size_t)kt * 64) * 2 + (size_t)((ch ^ (row & 7)) << 4);
      gload_lds16((const char*)Ab + gofs, (char*)As + (w * 4 + i) * 1024);
      gload_lds16((const char*)Bb + gofs, (char*)Bs + (w * 4 + i) * 1024);
    }
    __syncthreads();
#pragma unroll
    for (int s = 0; s < 2; ++s) {
      bf16x8 af[4], bf_[4];
#pragma unroll
      for (int mi = 0; mi < 4; ++mi) {
        int row = wm * 64 + mi * 16 + (lane & 15);
        af[mi] = *(const bf16x8*)((const char*)As +
                  ((row * 128 + s * 64 + (lane >> 4) * 16) ^ ((row & 7) << 4)));
      }
#pragma unroll
      for (int ni = 0; ni < 4; ++ni) {
        int row = wn * 64 + ni * 16 + (lane & 15);
        bf_[ni] = *(const bf16x8*)((const char*)Bs +
                  ((row * 128 + s * 64 + (lane >> 4) * 16) ^ ((row & 7) << 4)));
      }
#pragma unroll
      for (int mi = 0; mi < 4; ++mi)
#pragma unroll
        for (int ni = 0; ni < 4; ++ni)
          acc[mi * 4 + ni] = MFMA(af[mi], bf_[ni], acc[mi * 4 + ni]);
    }
  }
#pragma unroll
  for (int ni = 0; ni < 4; ++ni) {
    int col = bn * 128 + wn * 64 + ni * 16 + (lane & 15);
#pragma unroll
    for (int mi = 0; mi < 4; ++mi) {
#pragma unroll
      for (int e = 0; e < 4; ++e) {
        int qr = bm * 128 + wm * 64 + mi * 16 + (lane >> 4) * 4 + e;
        O[(size_t)(b * 2048 + qr) * 1024 + col] = acc[mi * 4 + ni][e];
      }
    }
  }
}

extern "C" void kernel_launch(void* const* d_in, const int* in_sizes, int n_in,
                              void* d_out, int out_size, void* d_ws, size_t ws_size,
                              hipStream_t stream) {
  const float* x  = (const float*)d_in[0];
  const int* mask = (const int*)d_in[1];
  const float* Wq = (const float*)d_in[2];
  const float* bq = (const float*)d_in[3];
  const float* Wk = (const float*)d_in[4];
  const float* bk = (const float*)d_in[5];
  const float* Wv = (const float*)d_in[6];
  const float* bv = (const float*)d_in[7];
  float* out = (float*)d_out;

  char* ws = (char*)d_ws;
  // ws layout (bytes): xb 0..32M | wt 32M..38.3M | q 38.3M..71.9M | k 71.9M..105.4M | v 105.4M..139M
  bf16* xb = (bf16*)(ws);
  bf16* wt = (bf16*)(ws + 33554432);
  bf16* q  = (bf16*)(ws + 39845888);
  bf16* k  = (bf16*)(ws + 73400320);
  bf16* v  = (bf16*)(ws + 106954752);
  bf16* vt = xb;                    // xb dead after k_qkv
  bf16* S  = (bf16*)d_out;          // 16384x2048 bf16 = 64MB = out buffer exactly
  bf16* P  = q;                     // q+k slots (64MB contiguous), dead after k_qk

  k_cvt_x<<<8192, 256, 0, stream>>>(x, xb);
  k_cvt_w<<<1536, 256, 0, stream>>>(Wq, Wk, Wv, wt);
  k_qkv<<<dim3(128, 24), 256, 0, stream>>>(xb, wt, bq, bk, bv, q, k, v);
  k_trv<<<dim3(32, 16, 8), 256, 0, stream>>>(v, vt);
  k_qk<<<dim3(16, 16, 8), 256, 0, stream>>>(q, k, S);
  k_sm<<<16384, 256, 0, stream>>>(S, mask, P);
  k_pv<<<dim3(16, 8, 8), 256, 0, stream>>>(P, vt, out);
}